// Round 5
// baseline (231.975 us; speedup 1.0000x reference)
//
#include <hip/hip_runtime.h>
#include <hip/hip_bf16.h>
#include <hip/hip_cooperative_groups.h>
#include <math.h>

namespace cg = cooperative_groups;

#define N_NODES 4096
#define IN_F    128
#define HEADS   8
#define HIDDEN  8
#define OUTD    64   // HEADS*HIDDEN
#define SLOPE   0.2f
#define ECAP    256  // per-row edge cap: mean 82, sd 9 -> 19 sigma

// ---------------------------------------------------------------------------
// Single cooperative kernel, 1024 blocks x 256 threads (4 blocks/CU x 256 CU
// = exactly co-resident with __launch_bounds__(256,4) -> <=128 VGPR).
//
// Phase A (gemm): block b computes g = h@W and sl/sr projections for nodes
// 4b..4b+3. Per-wave f32-vs-bf16 self-detection (reinterpret h[0..511] as
// bf16: true-f32 gives |v|>1e4/NaN with per-wave miss prob ~5e-34); the flag
// stays in a register across the grid sync — no global flags round-trip.
//
// grid.sync(): replaces the second kernel launch (~5us) with a ~1-2us
// device barrier; __threadfence() (agent-scope release, emits L2 writeback
// on gfx950) makes g/sl/sr visible across XCDs.
//
// Phase B (attention): one wave per row (block b, wave w -> row 4b+w).
// Edge order is irrelevant to a softmax sum, so compaction needs no
// order-preserving ballot rounds: each lane builds a 64-bit neighbor mask,
// shfl_up-prefix over popcounts assigns segments, set bits scatter into the
// wave's private LDS edge list. Then 8 edge-slots x 8 heads register
// accumulation, shfl_xor reduce (masks 8/16/32), store. No __syncthreads in
// phase B at all. Adj layout (int32 vs byte) self-detected per wave from the
// first 1024 words (L2-hot; int32-bool words are 0/1, byte layout exceeds 1
// with miss prob ~1e-12 given ~20 set bytes in the window).
// ---------------------------------------------------------------------------
__global__ __launch_bounds__(256, 4) void gat_fused_kernel(
    const void* __restrict__ hraw, const void* __restrict__ Wraw,
    const void* __restrict__ alraw, const void* __restrict__ arraw,
    const void* __restrict__ adjraw,
    float* __restrict__ g, float* __restrict__ slArr, float* __restrict__ srArr,
    void* __restrict__ outraw) {

    __shared__ union SM {
        struct { float lh[4][IN_F]; float lg[4][OUTD]; } a;  // 3 KB (phase A)
        int edges[4][ECAP];                                  // 4 KB (phase B)
    } sm;

    const int tid  = threadIdx.x;
    const int wave = tid >> 6;
    const int lane = tid & 63;
    const int n0   = blockIdx.x * 4;

    // --- dtype detection (wave-uniform register, survives both phases) ---
    const __hip_bfloat16* hb = (const __hip_bfloat16*)hraw;
    float p0 = __bfloat162float(hb[tid]);
    float p1 = __bfloat162float(hb[tid + 256]);
    int bad = (!(fabsf(p0) < 1e4f)) | (!(fabsf(p1) < 1e4f));
    const int isF32 = (__ballot(bad) != 0ULL) ? 1 : 0;

    // ======================= Phase A: gemm =======================
    if (isF32) {
        const float2* hf = (const float2*)((const float*)hraw + (size_t)n0 * IN_F);
        ((float2*)&sm.a.lh[0][0])[tid] = hf[tid];
    } else {
        const ushort2* h2 = (const ushort2*)((const __hip_bfloat16*)hraw + (size_t)n0 * IN_F);
        ushort2 v = h2[tid];
        float2 f;
        f.x = __bfloat162float(*(__hip_bfloat16*)&v.x);
        f.y = __bfloat162float(*(__hip_bfloat16*)&v.y);
        ((float2*)&sm.a.lh[0][0])[tid] = f;
    }
    __syncthreads();

    {
        const int nn = tid >> 6;
        const int c  = tid & 63;
        float acc = 0.f;
        if (isF32) {
            const float* Wf = (const float*)Wraw;
            #pragma unroll 8
            for (int k = 0; k < IN_F; ++k) acc += sm.a.lh[nn][k] * Wf[k * OUTD + c];
        } else {
            const __hip_bfloat16* Wb = (const __hip_bfloat16*)Wraw;
            #pragma unroll 8
            for (int k = 0; k < IN_F; ++k) acc += sm.a.lh[nn][k] * __bfloat162float(Wb[k * OUTD + c]);
        }
        g[(size_t)(n0 + nn) * OUTD + c] = acc;
        sm.a.lg[nn][c] = acc;
    }
    __syncthreads();

    if (tid < 32) {
        const int m  = tid >> 3;
        const int hh = tid & 7;
        float sl = 0.f, sr = 0.f;
        if (isF32) {
            const float* al = (const float*)alraw;
            const float* ar = (const float*)arraw;
            #pragma unroll
            for (int d = 0; d < HIDDEN; ++d) {
                float gv = sm.a.lg[m][hh * HIDDEN + d];
                sl += gv * al[d]; sr += gv * ar[d];
            }
        } else {
            const __hip_bfloat16* al = (const __hip_bfloat16*)alraw;
            const __hip_bfloat16* ar = (const __hip_bfloat16*)arraw;
            #pragma unroll
            for (int d = 0; d < HIDDEN; ++d) {
                float gv = sm.a.lg[m][hh * HIDDEN + d];
                sl += gv * __bfloat162float(al[d]); sr += gv * __bfloat162float(ar[d]);
            }
        }
        slArr[(size_t)(n0 + m) * HEADS + hh] = sl;
        srArr[(size_t)(n0 + m) * HEADS + hh] = sr;
    }

    // =================== grid-wide sync ===================
    __threadfence();            // agent-scope release: flush g/sl/sr to L3
    cg::this_grid().sync();     // also serves as the block barrier for LDS reuse

    // ======================= Phase B: attention =======================
    const int row = n0 + wave;

    // adj layout detection (first 1024 words, L2-hot, per-wave)
    const uint4* a4 = (const uint4*)adjraw;
    uint4 det = a4[lane];
    int big = ((det.x | det.y | det.z | det.w) > 1u);
    const int byteadj = (__ballot(big) != 0ULL) ? 1 : 0;

    // --- build 64-bit neighbor mask for this lane's share of the row ---
    unsigned long long mask = 0ULL;
    if (byteadj) {
        const uint4* arow = (const uint4*)((const unsigned char*)adjraw + (size_t)row * N_NODES);
        #pragma unroll
        for (int c = 0; c < 4; ++c) {
            uint4 w = arow[c * 64 + lane];           // 16 bools
            unsigned int wc[4] = {w.x, w.y, w.z, w.w};
            unsigned long long bits = 0ULL;
            #pragma unroll
            for (int k = 0; k < 4; ++k)
                #pragma unroll
                for (int b = 0; b < 4; ++b)
                    if ((wc[k] >> (8 * b)) & 0xFFu) bits |= 1ULL << (k * 4 + b);
            mask |= bits << (c * 16);
        }
    } else {
        const uint4* arow = (const uint4*)((const int*)adjraw + (size_t)row * N_NODES);
        #pragma unroll
        for (int c = 0; c < 16; ++c) {
            uint4 w = arow[c * 64 + lane];           // 4 bools
            unsigned long long bits = (w.x ? 1ULL : 0ULL) | (w.y ? 2ULL : 0ULL)
                                    | (w.z ? 4ULL : 0ULL) | (w.w ? 8ULL : 0ULL);
            mask |= bits << (c * 4);
        }
    }

    // --- prefix over per-lane popcounts -> scatter set bits to LDS ---
    const int cnt = (int)__popcll(mask);
    int pre = cnt;
    #pragma unroll
    for (int m2 = 1; m2 < 64; m2 <<= 1) {
        int t = __shfl_up(pre, m2, 64);
        if (lane >= m2) pre += t;
    }
    const int excl  = pre - cnt;
    const int total = min(__builtin_amdgcn_readlane(pre, 63), ECAP);

    unsigned long long mm = mask;
    int p = excl;
    while (mm) {
        int k = (int)__builtin_ctzll(mm);
        mm &= mm - 1ULL;
        int node;
        if (byteadj) node = ((k >> 4) * 64 + lane) * 16 + (k & 15);
        else         node = (k >> 2) * 256 + lane * 4 + (k & 3);
        if (p < ECAP) sm.edges[wave][p] = node;
        ++p;
    }

    // --- gather / softmax: 8 edge-slots x 8 heads ---
    const int hh = lane & 7;
    const int s  = lane >> 3;
    const float sl_h = slArr[(size_t)row * HEADS + hh];

    float l = 0.f;
    float o[HIDDEN] = {0.f, 0.f, 0.f, 0.f, 0.f, 0.f, 0.f, 0.f};

    for (int e = s; e < total; e += 8) {
        int j = sm.edges[wave][e];
        float x = sl_h + srArr[(size_t)j * HEADS + hh];
        x = (x >= 0.f) ? x : SLOPE * x;
        float wgt = __expf(x);
        l += wgt;
        const float4* gp = (const float4*)(g + (size_t)j * OUTD + hh * HIDDEN);
        float4 g0 = gp[0], g1 = gp[1];
        o[0] += wgt * g0.x; o[1] += wgt * g0.y; o[2] += wgt * g0.z; o[3] += wgt * g0.w;
        o[4] += wgt * g1.x; o[5] += wgt * g1.y; o[6] += wgt * g1.z; o[7] += wgt * g1.w;
    }

    #pragma unroll
    for (int m2 = 8; m2 < 64; m2 <<= 1) {
        l += __shfl_xor(l, m2, 64);
        #pragma unroll
        for (int d = 0; d < HIDDEN; ++d) o[d] += __shfl_xor(o[d], m2, 64);
    }

    if (s == 0) {                                    // lanes 0..7, one per head
        const float inv = 1.0f / l;
        if (isF32) {
            float* op = (float*)outraw + (size_t)row * OUTD + hh * HIDDEN;
            float4 v0 = {o[0] * inv, o[1] * inv, o[2] * inv, o[3] * inv};
            float4 v1 = {o[4] * inv, o[5] * inv, o[6] * inv, o[7] * inv};
            ((float4*)op)[0] = v0;
            ((float4*)op)[1] = v1;
        } else {
            union { __hip_bfloat16 b[8]; uint4 v; } pk;
            #pragma unroll
            for (int d = 0; d < HIDDEN; ++d) pk.b[d] = __float2bfloat16(o[d] * inv);
            *(uint4*)((__hip_bfloat16*)outraw + (size_t)row * OUTD + hh * HIDDEN) = pk.v;
        }
    }
}

// ---------------------------------------------------------------------------
extern "C" void kernel_launch(void* const* d_in, const int* in_sizes, int n_in,
                              void* d_out, int out_size, void* d_ws, size_t ws_size,
                              hipStream_t stream) {
    const void* h   = d_in[0];
    const void* adj = d_in[1];
    const void* W   = d_in[2];
    const void* al  = d_in[3];
    const void* ar  = d_in[4];

    char* ws = (char*)d_ws;
    size_t off = 256;
    float* g   = (float*)(ws + off); off += (size_t)N_NODES * OUTD * 4;    // 1 MB
    float* slA = (float*)(ws + off); off += (size_t)N_NODES * HEADS * 4;   // 128 KB
    float* srA = (float*)(ws + off); off += (size_t)N_NODES * HEADS * 4;   // 128 KB

    void* args[] = {(void*)&h, (void*)&W, (void*)&al, (void*)&ar, (void*)&adj,
                    (void*)&g, (void*)&slA, (void*)&srA, (void*)&d_out};
    hipLaunchCooperativeKernel((const void*)gat_fused_kernel,
                               dim3(N_NODES / 4), dim3(256), args, 0, stream);
}

// Round 6
// 111.136 us; speedup vs baseline: 2.0873x; 2.0873x over previous
//
#include <hip/hip_runtime.h>
#include <hip/hip_bf16.h>
#include <math.h>

#define N_NODES 4096
#define IN_F    128
#define HEADS   8
#define HIDDEN  8
#define OUTD    64   // HEADS*HIDDEN
#define SLOPE   0.2f
#define SEGCAP  320  // per-wave edge segment cap (mean ~20.5, P(>320) ~ 0)

// ---------------------------------------------------------------------------
// Kernel 1: g = h @ W (4096x128 @ 128x64) + sl = g.a_l, sr = g.a_r.
// One block = 4 nodes, 256 threads. Per-wave f32-vs-bf16 self-detection.
// Block 0 scans the first 4096 adj words for byte-vs-int32 layout and
// publishes flags[0]=isF32, flags[1]=byteadj.
// (Round-3 champion structure: 110.8 us total; R4 split +6.3, R5 coop +121.)
// ---------------------------------------------------------------------------
__global__ __launch_bounds__(256) void gemm_kernel(
    const void* __restrict__ hraw, const void* __restrict__ Wraw,
    const void* __restrict__ alraw, const void* __restrict__ arraw,
    const void* __restrict__ adjraw,
    int* __restrict__ flags,
    float* __restrict__ g, float* __restrict__ slArr, float* __restrict__ srArr) {

    __shared__ float lh[4][IN_F];
    __shared__ float lg[4][OUTD];
    __shared__ int   bflag;

    const int tid = threadIdx.x;
    const int n0  = blockIdx.x * 4;

    // --- dtype detection (wave-uniform, no barrier needed) ---
    const __hip_bfloat16* hb = (const __hip_bfloat16*)hraw;
    float p0 = __bfloat162float(hb[tid]);
    float p1 = __bfloat162float(hb[tid + 256]);
    int bad = (!(fabsf(p0) < 1e4f)) | (!(fabsf(p1) < 1e4f));
    unsigned long long bm = __ballot(bad);
    const int isF32 = (bm != 0ULL) ? 1 : 0;

    // --- block 0: adj layout detection (first 4096 words = 16 KB) ---
    unsigned int adjbig = 0;
    if (blockIdx.x == 0) {
        if (tid == 0) bflag = 0;
        const uint4* a4 = (const uint4*)adjraw;
        uint4 d0 = a4[tid];
        uint4 d1 = a4[tid + 256];
        uint4 d2 = a4[tid + 512];
        uint4 d3 = a4[tid + 768];
        unsigned int m0 = d0.x | d0.y | d0.z | d0.w;
        unsigned int m1 = d1.x | d1.y | d1.z | d1.w;
        unsigned int m2 = d2.x | d2.y | d2.z | d2.w;
        unsigned int m3 = d3.x | d3.y | d3.z | d3.w;
        adjbig = ((m0 | m1 | m2 | m3) > 1u);
    }

    // --- stage 4 h-rows (512 floats) into LDS, 2 elems/thread vectorized ---
    if (isF32) {
        const float2* hf = (const float2*)((const float*)hraw + (size_t)n0 * IN_F);
        ((float2*)&lh[0][0])[tid] = hf[tid];
    } else {
        const ushort2* h2 = (const ushort2*)((const __hip_bfloat16*)hraw + (size_t)n0 * IN_F);
        ushort2 v = h2[tid];
        float2 f;
        f.x = __bfloat162float(*(__hip_bfloat16*)&v.x);
        f.y = __bfloat162float(*(__hip_bfloat16*)&v.y);
        ((float2*)&lh[0][0])[tid] = f;
    }
    __syncthreads();

    if (blockIdx.x == 0) {
        unsigned long long bm2 = __ballot(adjbig != 0);
        if ((tid & 63) == 0 && bm2 != 0ULL) atomicOr(&bflag, 1);
    }

    const int nn = tid >> 6;
    const int c  = tid & 63;
    float acc = 0.f;
    if (isF32) {
        const float* Wf = (const float*)Wraw;
        #pragma unroll 8
        for (int k = 0; k < IN_F; ++k) acc += lh[nn][k] * Wf[k * OUTD + c];
    } else {
        const __hip_bfloat16* Wb = (const __hip_bfloat16*)Wraw;
        #pragma unroll 8
        for (int k = 0; k < IN_F; ++k) acc += lh[nn][k] * __bfloat162float(Wb[k * OUTD + c]);
    }
    g[(size_t)(n0 + nn) * OUTD + c] = acc;
    lg[nn][c] = acc;
    __syncthreads();

    if (blockIdx.x == 0 && tid == 0) {
        flags[0] = isF32;
        flags[1] = bflag;
    }

    if (tid < 32) {
        const int m  = tid >> 3;
        const int hh = tid & 7;
        float sl = 0.f, sr = 0.f;
        if (isF32) {
            const float* al = (const float*)alraw;
            const float* ar = (const float*)arraw;
            #pragma unroll
            for (int d = 0; d < HIDDEN; ++d) {
                float gv = lg[m][hh * HIDDEN + d];
                sl += gv * al[d]; sr += gv * ar[d];
            }
        } else {
            const __hip_bfloat16* al = (const __hip_bfloat16*)alraw;
            const __hip_bfloat16* ar = (const __hip_bfloat16*)arraw;
            #pragma unroll
            for (int d = 0; d < HIDDEN; ++d) {
                float gv = lg[m][hh * HIDDEN + d];
                sl += gv * __bfloat162float(al[d]); sr += gv * __bfloat162float(ar[d]);
            }
        }
        slArr[(size_t)(n0 + m) * HEADS + hh] = sl;
        srArr[(size_t)(n0 + m) * HEADS + hh] = sr;
    }
}

// ---------------------------------------------------------------------------
// Kernel 2: attention. One block per row i, 256 threads = 4 waves.
// Each wave owns 1/4 of the adj row: ballot-compacts set bits into its
// private LDS segment (no LDS atomics, no barriers), processes its own
// edges (8 slots x 8 heads), shfl_xor reduces, single __syncthreads,
// cross-wave combine, store.
// ---------------------------------------------------------------------------
__global__ __launch_bounds__(256) void attn_kernel(
    const void* __restrict__ adjraw, const int* __restrict__ flags,
    const float* __restrict__ g,
    const float* __restrict__ slArr, const float* __restrict__ srArr,
    void* __restrict__ outraw) {

    const int i    = blockIdx.x;
    const int tid  = threadIdx.x;
    const int wave = tid >> 6;
    const int lane = tid & 63;

    __shared__ int   edges[4][SEGCAP];
    __shared__ float red[4][HEADS * 9];   // [wave][h*9 + {0..7: o, 8: l}]

    const int byteadj = __builtin_amdgcn_readfirstlane(flags[1]);
    const int isF32   = __builtin_amdgcn_readfirstlane(flags[0]);

    // prefetch this row's sl for our head (scattered L2 load — overlap it
    // under the compaction ballot chain)
    const int hh = lane & 7;
    const int s  = lane >> 3;
    const float sl_h = slArr[(size_t)i * HEADS + hh];

    // --- wave-local scan + ballot compaction (16 flags/lane) ---
    unsigned int fl[16];
    if (byteadj) {
        const uint4* arow = (const uint4*)((const unsigned char*)adjraw + (size_t)i * N_NODES);
        uint4 w = arow[wave * 64 + lane];            // 16 bools
        unsigned int wc[4] = {w.x, w.y, w.z, w.w};
        #pragma unroll
        for (int r = 0; r < 16; ++r) fl[r] = (wc[r >> 2] >> (8 * (r & 3))) & 0xFFu;
    } else {
        const uint4* arow = (const uint4*)((const int*)adjraw + (size_t)i * N_NODES);
        uint4 w0 = arow[wave * 256 + lane];          // issue all 4 loads up front
        uint4 w1 = arow[wave * 256 + 64 + lane];
        uint4 w2 = arow[wave * 256 + 128 + lane];
        uint4 w3 = arow[wave * 256 + 192 + lane];
        fl[0]=w0.x;  fl[1]=w0.y;  fl[2]=w0.z;  fl[3]=w0.w;
        fl[4]=w1.x;  fl[5]=w1.y;  fl[6]=w1.z;  fl[7]=w1.w;
        fl[8]=w2.x;  fl[9]=w2.y;  fl[10]=w2.z; fl[11]=w2.w;
        fl[12]=w3.x; fl[13]=w3.y; fl[14]=w3.z; fl[15]=w3.w;
    }

    const unsigned long long lmask = (1ULL << lane) - 1ULL;
    int wcnt = 0;
    #pragma unroll
    for (int r = 0; r < 16; ++r) {
        unsigned long long m = __ballot(fl[r] != 0u);
        if (fl[r]) {
            int node = byteadj ? (wave * 1024 + lane * 16 + r)
                               : (wave * 1024 + (r >> 2) * 256 + lane * 4 + (r & 3));
            int p = wcnt + (int)__popcll(m & lmask);
            if (p < SEGCAP) edges[wave][p] = node;
        }
        wcnt += (int)__popcll(m);
    }
    const int myE = min(wcnt, SEGCAP);               // wave-uniform

    // --- edge loop over this wave's own segment (no barrier needed) ---
    float l = 0.f;
    float o[HIDDEN] = {0.f, 0.f, 0.f, 0.f, 0.f, 0.f, 0.f, 0.f};

    for (int e = s; e < myE; e += 8) {
        int j = edges[wave][e];
        float x = sl_h + srArr[(size_t)j * HEADS + hh];
        x = (x >= 0.f) ? x : SLOPE * x;
        float wgt = __expf(x);
        l += wgt;
        const float4* gp = (const float4*)(g + (size_t)j * OUTD + hh * HIDDEN);
        float4 g0 = gp[0], g1 = gp[1];
        o[0] += wgt * g0.x; o[1] += wgt * g0.y; o[2] += wgt * g0.z; o[3] += wgt * g0.w;
        o[4] += wgt * g1.x; o[5] += wgt * g1.y; o[6] += wgt * g1.z; o[7] += wgt * g1.w;
    }

    // wave-level reduce over the 8 slots (xor 8/16/32 keeps hh fixed)
    #pragma unroll
    for (int m = 8; m < 64; m <<= 1) {
        l += __shfl_xor(l, m, 64);
        #pragma unroll
        for (int d = 0; d < HIDDEN; ++d) o[d] += __shfl_xor(o[d], m, 64);
    }
    if (s == 0) {                                    // lanes 0..7: one per head
        red[wave][hh * 9 + 8] = l;
        #pragma unroll
        for (int d = 0; d < HIDDEN; ++d) red[wave][hh * 9 + d] = o[d];
    }
    __syncthreads();                                 // the only barrier

    if (tid < OUTD) {
        const int h2 = tid >> 3, d2 = tid & 7;
        float os = 0.f, ls = 0.f;
        #pragma unroll
        for (int w = 0; w < 4; ++w) {
            os += red[w][h2 * 9 + d2];
            ls += red[w][h2 * 9 + 8];
        }
        float val = os / ls;
        if (isF32) {
            ((float*)outraw)[(size_t)i * OUTD + tid] = val;
        } else {
            ((__hip_bfloat16*)outraw)[(size_t)i * OUTD + tid] = __float2bfloat16(val);
        }
    }
}

// ---------------------------------------------------------------------------
extern "C" void kernel_launch(void* const* d_in, const int* in_sizes, int n_in,
                              void* d_out, int out_size, void* d_ws, size_t ws_size,
                              hipStream_t stream) {
    const void* h   = d_in[0];
    const void* adj = d_in[1];
    const void* W   = d_in[2];
    const void* al  = d_in[3];
    const void* ar  = d_in[4];

    char* ws = (char*)d_ws;
    int*   flags = (int*)ws;                                          // [0]=isF32, [1]=byteadj
    float* g     = (float*)(ws + 256);                                // 1 MB
    float* slA   = (float*)(ws + 256 + (size_t)N_NODES * OUTD * 4);   // 128 KB
    float* srA   = (float*)(ws + 256 + (size_t)N_NODES * OUTD * 4
                                   + (size_t)N_NODES * HEADS * 4);    // 128 KB

    gemm_kernel<<<N_NODES / 4, 256, 0, stream>>>(h, W, al, ar, adj, flags, g, slA, srA);
    attn_kernel<<<N_NODES, 256, 0, stream>>>(adj, flags, g, slA, srA, d_out);
}